// Round 5
// baseline (128.784 us; speedup 1.0000x reference)
//
#include <hip/hip_runtime.h>

// Problem constants (from reference)
#define QQ 16
#define NQ 128
#define HH 256
#define P5 1024   // 4^5
#define LOG2E   1.44269504088896340f
#define K2LOG2E 2.88539008177792681f  // 2*log2(e)

// ---------------------------------------------------------------------------
// Block-wide sum over 256 threads (4 waves). All threads return the total.
// ---------------------------------------------------------------------------
__device__ __forceinline__ float block_sum256(float v, float* red, int t) {
#pragma unroll
  for (int o = 32; o > 0; o >>= 1) v += __shfl_down(v, o, 64);
  if ((t & 63) == 0) red[t >> 6] = v;
  __syncthreads();
  float r = red[0] + red[1] + red[2] + red[3];
  __syncthreads();
  return r;
}

// ---------------------------------------------------------------------------
// Prep kernel — 256 blocks x 256 threads. Every block redundantly computes
// the tiny rhs vector in LDS, then block hb computes w2r[hb] =
// dot(Wx2[hb,:], rhs) with a coalesced 4KB row read.
// Output (SoA, constants FOLDED so main's inner loop is minimal):
//   ws[      h] = K2LOG2E * Wx1[0][h]
//   ws[ 256 + h] = K2LOG2E * Wx1[1][h]
//   ws[ 512 + h] = K2LOG2E * Wx1[2][h]
//   ws[ 768 + h] = K2LOG2E * bx1[h]
//   ws[1024 + h] = -2 * w2r[h]
//   ws[1280]     = b2r = dot(bx2, rhs)
// ---------------------------------------------------------------------------
__global__ __launch_bounds__(256) void prep_kernel(
    const float* __restrict__ eq,
    const float* __restrict__ q0, const float* __restrict__ q1,
    const float* __restrict__ q2, const float* __restrict__ q3,
    const float* __restrict__ q4,
    const float* __restrict__ Wx1, const float* __restrict__ bx1,
    const float* __restrict__ Wx2, const float* __restrict__ bx2,
    const float* __restrict__ Wq0, const float* __restrict__ bq0,
    const float* __restrict__ Wq1, const float* __restrict__ bq1,
    const float* __restrict__ Wq2, const float* __restrict__ bq2,
    const float* __restrict__ Wq3, const float* __restrict__ bq3,
    const float* __restrict__ Wq4, const float* __restrict__ bq4,
    float* __restrict__ ws) {
  __shared__ float sS[5][64];
  __shared__ float sRhs[P5];
  __shared__ float sPart[4][10];
  __shared__ float sAB[10];
  __shared__ float red[4];

  const int t = threadIdx.x;
  const int hb = blockIdx.x;
  const float c = -eq[0] * LOG2E;  // y = exp(-x^2*eq) = exp2(x^2 * c)

  const float* qs[5]  = {q0, q1, q2, q3, q4};
  const float* Wqs[5] = {Wq0, Wq1, Wq2, Wq3, Wq4};
  const float* bqs[5] = {bq0, bq1, bq2, bq3, bq4};

  // A_i = sum_r y*qx (v[2i]), B_i = sum_r y (v[2i+1])
  float v[10];
#pragma unroll
  for (int i = 0; i < 5; ++i) {
    float a = 0.f, b = 0.f;
    if (t < NQ) {
      float x = qs[i][t];
      float y = exp2f(x * x * c);
      a = y * x;
      b = y;
    }
    v[2 * i] = a;
    v[2 * i + 1] = b;
  }
#pragma unroll
  for (int k = 0; k < 10; ++k) {
    float s = v[k];
#pragma unroll
    for (int o = 32; o > 0; o >>= 1) s += __shfl_down(s, o, 64);
    if ((t & 63) == 0) sPart[t >> 6][k] = s;
  }
  __syncthreads();
  if (t < 10) sAB[t] = sPart[0][t] + sPart[1][t] + sPart[2][t] + sPart[3][t];
  __syncthreads();

  // s_i[j] = Wq_i[j]*A_i + bq_i[j]*B_i   (5 x 64)
  for (int k = t; k < 5 * 64; k += 256) {
    int i = k >> 6, j = k & 63;
    sS[i][j] = Wqs[i][j] * sAB[2 * i] + bqs[i][j] * sAB[2 * i + 1];
  }
  __syncthreads();

  // rhs[idx] = sum_x s0[b,x] s1[d,x] s2[f,x] s3[m,x] s4[v,x]
  for (int idx = t; idx < P5; idx += 256) {
    int b = (idx >> 8) & 3, d = (idx >> 6) & 3, f = (idx >> 4) & 3,
        m = (idx >> 2) & 3, w = idx & 3;
    float s = 0.f;
#pragma unroll
    for (int x = 0; x < QQ; ++x)
      s += sS[0][b * QQ + x] * sS[1][d * QQ + x] * sS[2][f * QQ + x] *
           sS[3][m * QQ + x] * sS[4][w * QQ + x];
    sRhs[idx] = s;
  }
  __syncthreads();

  // w2r[hb] = dot(Wx2[hb,:], rhs)
  const float* wrow = Wx2 + hb * P5;
  float p = 0.f;
#pragma unroll
  for (int k = 0; k < 4; ++k)
    p = fmaf(wrow[t + 256 * k], sRhs[t + 256 * k], p);
  p = block_sum256(p, red, t);

  if (t == 0) {
    ws[hb]            = K2LOG2E * Wx1[hb];
    ws[HH + hb]       = K2LOG2E * Wx1[HH + hb];
    ws[2 * HH + hb]   = K2LOG2E * Wx1[2 * HH + hb];
    ws[3 * HH + hb]   = K2LOG2E * bx1[hb];
    ws[4 * HH + hb]   = -2.0f * p;
  }

  if (hb == 0) {
    float pb = 0.f;
    for (int j = t; j < P5; j += 256) pb = fmaf(bx2[j], sRhs[j], pb);
    pb = block_sum256(pb, red, t);
    if (t == 0) ws[5 * HH] = pb;
  }
}

// ---------------------------------------------------------------------------
// Main kernel: out[i] = CONST + sum_h wr'[h] / (1 + exp2(x_i.w'_h + b'_h))
// where CONST = b2r + Sum w2r = b2r - 0.5*Sum wr'.
// ONE WAVE PER BLOCK, one row per lane. The entire 256-h table lives in
// 20 VGPRs/lane (lane l holds h = s*64+l, s=0..3). The h-loop is wave-
// uniform, so each h's 5 params are broadcast via v_readlane_b32 (VALU
// pipe) — ZERO LDS / VMEM in the inner loop. 1563 blocks ≈ 1.5 waves/SIMD
// so neighbor waves overlap VALU with the trans (exp2/rcp) pipe.
// ---------------------------------------------------------------------------
__device__ __forceinline__ float rd_lane(float v, int l) {
  return __builtin_bit_cast(
      float, __builtin_amdgcn_readlane(__builtin_bit_cast(int, v), l));
}

__global__ __launch_bounds__(64) void main_kernel(
    const float* __restrict__ input, const float* __restrict__ ws,
    float* __restrict__ out, int n) {
  const int lane = threadIdx.x;  // 0..63

  // stage the table: 20 VGPRs per lane, coalesced global reads (L2-hot)
  float vw0[4], vw1[4], vw2[4], vb[4], vwr[4];
#pragma unroll
  for (int s = 0; s < 4; ++s) {
    const int h = s * 64 + lane;
    vw0[s] = ws[h];
    vw1[s] = ws[HH + h];
    vw2[s] = ws[2 * HH + h];
    vb[s]  = ws[3 * HH + h];
    vwr[s] = ws[4 * HH + h];
  }

  // CONST = b2r - 0.5 * sum_h wr'  (one-time butterfly, off the hot loop)
  float ls = (vwr[0] + vwr[1]) + (vwr[2] + vwr[3]);
#pragma unroll
  for (int o = 32; o > 0; o >>= 1) ls += __shfl_xor(ls, o, 64);
  const float CONST = fmaf(-0.5f, ls, ws[5 * HH]);

  const int row = blockIdx.x * 64 + lane;
  const bool valid = row < n;
  float x0 = 0.f, x1 = 0.f, x2 = 0.f;
  if (valid) {
    x0 = input[row * 3 + 0];
    x1 = input[row * 3 + 1];
    x2 = input[row * 3 + 2];
  }

  float acc0 = 0.f, acc1 = 0.f;
#pragma unroll
  for (int s = 0; s < 4; ++s) {
#pragma unroll 8
    for (int j = 0; j < 64; j += 2) {
      {
        const float w0 = rd_lane(vw0[s], j);
        const float w1 = rd_lane(vw1[s], j);
        const float w2 = rd_lane(vw2[s], j);
        const float b  = rd_lane(vb[s],  j);
        const float wr = rd_lane(vwr[s], j);
        float a = fmaf(w2, x2, fmaf(w1, x1, fmaf(w0, x0, b)));
        float r = __builtin_amdgcn_rcpf(exp2f(a) + 1.0f);  // inf -> 0, ok
        acc0 = fmaf(wr, r, acc0);
      }
      {
        const float w0 = rd_lane(vw0[s], j + 1);
        const float w1 = rd_lane(vw1[s], j + 1);
        const float w2 = rd_lane(vw2[s], j + 1);
        const float b  = rd_lane(vb[s],  j + 1);
        const float wr = rd_lane(vwr[s], j + 1);
        float a = fmaf(w2, x2, fmaf(w1, x1, fmaf(w0, x0, b)));
        float r = __builtin_amdgcn_rcpf(exp2f(a) + 1.0f);
        acc1 = fmaf(wr, r, acc1);
      }
    }
  }

  if (valid) out[row] = (acc0 + acc1) + CONST;
}

// ---------------------------------------------------------------------------
extern "C" void kernel_launch(void* const* d_in, const int* in_sizes, int n_in,
                              void* d_out, int out_size, void* d_ws,
                              size_t ws_size, hipStream_t stream) {
  const float* input = (const float*)d_in[0];
  const float* eq    = (const float*)d_in[1];
  const float* q0    = (const float*)d_in[2];
  const float* q1    = (const float*)d_in[3];
  const float* q2    = (const float*)d_in[4];
  const float* q3    = (const float*)d_in[5];
  const float* q4    = (const float*)d_in[6];
  const float* Wx1   = (const float*)d_in[7];
  const float* bx1   = (const float*)d_in[8];
  const float* Wx2   = (const float*)d_in[9];
  const float* bx2   = (const float*)d_in[10];
  const float* Wq0   = (const float*)d_in[11];
  const float* bq0   = (const float*)d_in[12];
  const float* Wq1   = (const float*)d_in[13];
  const float* bq1   = (const float*)d_in[14];
  const float* Wq2   = (const float*)d_in[15];
  const float* bq2   = (const float*)d_in[16];
  const float* Wq3   = (const float*)d_in[17];
  const float* bq3   = (const float*)d_in[18];
  const float* Wq4   = (const float*)d_in[19];
  const float* bq4   = (const float*)d_in[20];

  float* ws  = (float*)d_ws;
  float* out = (float*)d_out;
  const int n = in_sizes[0] / 3;  // N = 100000

  hipLaunchKernelGGL(prep_kernel, dim3(HH), dim3(256), 0, stream,
                     eq, q0, q1, q2, q3, q4, Wx1, bx1, Wx2, bx2,
                     Wq0, bq0, Wq1, bq1, Wq2, bq2, Wq3, bq3, Wq4, bq4, ws);

  const int blocks = (n + 63) / 64;  // one wave per block, one row per lane
  hipLaunchKernelGGL(main_kernel, dim3(blocks), dim3(64), 0, stream,
                     input, ws, out, n);
}

// Round 6
// 115.762 us; speedup vs baseline: 1.1125x; 1.1125x over previous
//
#include <hip/hip_runtime.h>

// Problem constants (from reference)
#define QQ 16
#define NQ 128
#define HH 256
#define P5 1024   // 4^5
#define LOG2E   1.44269504088896340f
#define K2LOG2E 2.88539008177792681f  // 2*log2(e)

// ---------------------------------------------------------------------------
// Block-wide sum over 256 threads (4 waves). All threads return the total.
// ---------------------------------------------------------------------------
__device__ __forceinline__ float block_sum256(float v, float* red, int t) {
#pragma unroll
  for (int o = 32; o > 0; o >>= 1) v += __shfl_down(v, o, 64);
  if ((t & 63) == 0) red[t >> 6] = v;
  __syncthreads();
  float r = red[0] + red[1] + red[2] + red[3];
  __syncthreads();
  return r;
}

// ---------------------------------------------------------------------------
// Prep kernel — 256 blocks x 256 threads. Every block redundantly computes
// the tiny rhs vector in LDS, then block hb computes w2r[hb] =
// dot(Wx2[hb,:], rhs) with a coalesced 4KB row read.
// Output (SoA, constants FOLDED so main's inner loop is minimal):
//   ws[       h] = K2LOG2E * Wx1[0][h]
//   ws[ 256 + h] = K2LOG2E * Wx1[1][h]
//   ws[ 512 + h] = K2LOG2E * Wx1[2][h]
//   ws[ 768 + h] = K2LOG2E * bx1[h]
//   ws[1024 + h] = -2 * w2r[h]
//   ws[1280]     = b2r = dot(bx2, rhs)
// ---------------------------------------------------------------------------
__global__ __launch_bounds__(256) void prep_kernel(
    const float* __restrict__ eq,
    const float* __restrict__ q0, const float* __restrict__ q1,
    const float* __restrict__ q2, const float* __restrict__ q3,
    const float* __restrict__ q4,
    const float* __restrict__ Wx1, const float* __restrict__ bx1,
    const float* __restrict__ Wx2, const float* __restrict__ bx2,
    const float* __restrict__ Wq0, const float* __restrict__ bq0,
    const float* __restrict__ Wq1, const float* __restrict__ bq1,
    const float* __restrict__ Wq2, const float* __restrict__ bq2,
    const float* __restrict__ Wq3, const float* __restrict__ bq3,
    const float* __restrict__ Wq4, const float* __restrict__ bq4,
    float* __restrict__ ws) {
  __shared__ float sS[5][64];
  __shared__ float sRhs[P5];
  __shared__ float sPart[4][10];
  __shared__ float sAB[10];
  __shared__ float red[4];

  const int t = threadIdx.x;
  const int hb = blockIdx.x;
  const float c = -eq[0] * LOG2E;  // y = exp(-x^2*eq) = exp2(x^2 * c)

  const float* qs[5]  = {q0, q1, q2, q3, q4};
  const float* Wqs[5] = {Wq0, Wq1, Wq2, Wq3, Wq4};
  const float* bqs[5] = {bq0, bq1, bq2, bq3, bq4};

  // A_i = sum_r y*qx (v[2i]), B_i = sum_r y (v[2i+1])
  float v[10];
#pragma unroll
  for (int i = 0; i < 5; ++i) {
    float a = 0.f, b = 0.f;
    if (t < NQ) {
      float x = qs[i][t];
      float y = exp2f(x * x * c);
      a = y * x;
      b = y;
    }
    v[2 * i] = a;
    v[2 * i + 1] = b;
  }
#pragma unroll
  for (int k = 0; k < 10; ++k) {
    float s = v[k];
#pragma unroll
    for (int o = 32; o > 0; o >>= 1) s += __shfl_down(s, o, 64);
    if ((t & 63) == 0) sPart[t >> 6][k] = s;
  }
  __syncthreads();
  if (t < 10) sAB[t] = sPart[0][t] + sPart[1][t] + sPart[2][t] + sPart[3][t];
  __syncthreads();

  // s_i[j] = Wq_i[j]*A_i + bq_i[j]*B_i   (5 x 64)
  for (int k = t; k < 5 * 64; k += 256) {
    int i = k >> 6, j = k & 63;
    sS[i][j] = Wqs[i][j] * sAB[2 * i] + bqs[i][j] * sAB[2 * i + 1];
  }
  __syncthreads();

  // rhs[idx] = sum_x s0[b,x] s1[d,x] s2[f,x] s3[m,x] s4[v,x]
  for (int idx = t; idx < P5; idx += 256) {
    int b = (idx >> 8) & 3, d = (idx >> 6) & 3, f = (idx >> 4) & 3,
        m = (idx >> 2) & 3, w = idx & 3;
    float s = 0.f;
#pragma unroll
    for (int x = 0; x < QQ; ++x)
      s += sS[0][b * QQ + x] * sS[1][d * QQ + x] * sS[2][f * QQ + x] *
           sS[3][m * QQ + x] * sS[4][w * QQ + x];
    sRhs[idx] = s;
  }
  __syncthreads();

  // w2r[hb] = dot(Wx2[hb,:], rhs)
  const float* wrow = Wx2 + hb * P5;
  float p = 0.f;
#pragma unroll
  for (int k = 0; k < 4; ++k)
    p = fmaf(wrow[t + 256 * k], sRhs[t + 256 * k], p);
  p = block_sum256(p, red, t);

  if (t == 0) {
    ws[hb]          = K2LOG2E * Wx1[hb];
    ws[HH + hb]     = K2LOG2E * Wx1[HH + hb];
    ws[2 * HH + hb] = K2LOG2E * Wx1[2 * HH + hb];
    ws[3 * HH + hb] = K2LOG2E * bx1[hb];
    ws[4 * HH + hb] = -2.0f * p;
  }

  if (hb == 0) {
    float pb = 0.f;
    for (int j = t; j < P5; j += 256) pb = fmaf(bx2[j], sRhs[j], pb);
    pb = block_sum256(pb, red, t);
    if (t == 0) ws[5 * HH] = pb;
  }
}

// ---------------------------------------------------------------------------
// Main kernel: out[i] = CONST + sum_h wr'[h] / (1 + exp2(x_i.w'_h + b'_h))
// where wr' = -2*w2r, CONST = b2r + Sum w2r = b2r - 0.5*Sum wr'.
//
// Structure (the two prior failures resolved simultaneously):
//  - 256-thread blocks; the 4 WAVES SPLIT the h dimension (64 h each) so
//    cross-wave partials are combined once via LDS at the end.
//  - R=4 rows per lane -> each LDS table read serves 4 rows (table traffic
//    /4), rows/block = 256 -> grid = 391 blocks >= 256 CUs (no
//    under-dispatch like R4's 196, no vmem storm like R2, no readlane VALU
//    tax like R5).
// Inner loop: 1 broadcast ds_read_b128 per h (+1 per 4 h) and per row
// 5 VALU + 2 trans. Per-CU budgets: LDS ~2.4us, trans ~2.6us, VALU ~2us,
// all on different pipes.
// ---------------------------------------------------------------------------
__global__ __launch_bounds__(256) void main_kernel(
    const float* __restrict__ input, const float* __restrict__ ws,
    float* __restrict__ out, int n) {
  __shared__ float4 qtab[HH];         // {w0,w1,w2,b} (K2LOG2E folded)
  __shared__ float4 wtab4[HH / 4];    // -2*w2r
  __shared__ float red[4];
  __shared__ float sred[4][4][64];    // [wave][r][lane] partials

  const int t = threadIdx.x;
  const int lane = t & 63;
  const int wv = t >> 6;

  // ---- stage table (thread t owns h = t; coalesced global reads) ----
  const float w0 = ws[t], w1 = ws[HH + t], w2 = ws[2 * HH + t];
  const float bb = ws[3 * HH + t], wr = ws[4 * HH + t];
  qtab[t] = make_float4(w0, w1, w2, bb);
  ((float*)wtab4)[t] = wr;

  // butterfly Sum wr within each wave; combine across waves via red[]
  float s = wr;
#pragma unroll
  for (int o = 32; o > 0; o >>= 1) s += __shfl_xor(s, o, 64);
  if (lane == 0) red[wv] = s;
  __syncthreads();  // covers qtab/wtab4/red
  const float CONST = fmaf(-0.5f, (red[0] + red[1]) + (red[2] + red[3]),
                           ws[5 * HH]);

  // ---- 4 rows per lane (same 256 rows for all 4 waves; h differs) ----
  const int row0 = blockIdx.x * 256;
  float x0[4], x1[4], x2[4], acc[4];
#pragma unroll
  for (int r = 0; r < 4; ++r) {
    const int row = row0 + r * 64 + lane;
    x0[r] = x1[r] = x2[r] = 0.f;
    if (row < n) {
      x0[r] = input[row * 3 + 0];
      x1[r] = input[row * 3 + 1];
      x2[r] = input[row * 3 + 2];
    }
    acc[r] = 0.f;
  }

  const int hbase = wv * 64;
#pragma unroll 4
  for (int j = 0; j < 16; ++j) {
    const float4 wq = wtab4[wv * 16 + j];
    const float wrv[4] = {wq.x, wq.y, wq.z, wq.w};
#pragma unroll
    for (int u = 0; u < 4; ++u) {
      const float4 q = qtab[hbase + j * 4 + u];
#pragma unroll
      for (int r = 0; r < 4; ++r) {
        float a = fmaf(q.z, x2[r], fmaf(q.y, x1[r], fmaf(q.x, x0[r], q.w)));
        float rc = __builtin_amdgcn_rcpf(exp2f(a) + 1.0f);  // inf -> 0, ok
        acc[r] = fmaf(wrv[u], rc, acc[r]);
      }
    }
  }

  // ---- combine the 4 waves' h-partials ----
#pragma unroll
  for (int r = 0; r < 4; ++r) sred[wv][r][lane] = acc[r];
  __syncthreads();

  {  // thread t finalizes row group rr = t>>6, lane = t&63
    const int rr = wv;
    const int row = row0 + rr * 64 + lane;
    if (row < n) {
      float sum = (sred[0][rr][lane] + sred[1][rr][lane]) +
                  (sred[2][rr][lane] + sred[3][rr][lane]);
      out[row] = sum + CONST;
    }
  }
}

// ---------------------------------------------------------------------------
extern "C" void kernel_launch(void* const* d_in, const int* in_sizes, int n_in,
                              void* d_out, int out_size, void* d_ws,
                              size_t ws_size, hipStream_t stream) {
  const float* input = (const float*)d_in[0];
  const float* eq    = (const float*)d_in[1];
  const float* q0    = (const float*)d_in[2];
  const float* q1    = (const float*)d_in[3];
  const float* q2    = (const float*)d_in[4];
  const float* q3    = (const float*)d_in[5];
  const float* q4    = (const float*)d_in[6];
  const float* Wx1   = (const float*)d_in[7];
  const float* bx1   = (const float*)d_in[8];
  const float* Wx2   = (const float*)d_in[9];
  const float* bx2   = (const float*)d_in[10];
  const float* Wq0   = (const float*)d_in[11];
  const float* bq0   = (const float*)d_in[12];
  const float* Wq1   = (const float*)d_in[13];
  const float* bq1   = (const float*)d_in[14];
  const float* Wq2   = (const float*)d_in[15];
  const float* bq2   = (const float*)d_in[16];
  const float* Wq3   = (const float*)d_in[17];
  const float* bq3   = (const float*)d_in[18];
  const float* Wq4   = (const float*)d_in[19];
  const float* bq4   = (const float*)d_in[20];

  float* ws  = (float*)d_ws;
  float* out = (float*)d_out;
  const int n = in_sizes[0] / 3;  // N = 100000

  hipLaunchKernelGGL(prep_kernel, dim3(HH), dim3(256), 0, stream,
                     eq, q0, q1, q2, q3, q4, Wx1, bx1, Wx2, bx2,
                     Wq0, bq0, Wq1, bq1, Wq2, bq2, Wq3, bq3, Wq4, bq4, ws);

  const int blocks = (n + 255) / 256;  // 256 rows per block (R=4 per lane)
  hipLaunchKernelGGL(main_kernel, dim3(blocks), dim3(256), 0, stream,
                     input, ws, out, n);
}

// Round 7
// 111.377 us; speedup vs baseline: 1.1563x; 1.0394x over previous
//
#include <hip/hip_runtime.h>

// Problem constants (from reference)
#define QQ 16
#define NQ 128
#define HH 256
#define P5 1024   // 4^5
#define LOG2E   1.44269504088896340f
#define K2LOG2E 2.88539008177792681f  // 2*log2(e)

// Raw v_exp_f32 (1 ulp, flush-denorm): avoids the __ocml_exp2_f32 wrapper,
// which adds ~5 VALU insts of denormal-range handling per call. Our args
// only need denormal outputs when the sigmoid is 1.0 to 2^-126 accuracy,
// so the raw instruction is exact enough.
__device__ __forceinline__ float fast_exp2(float x) {
  return __builtin_amdgcn_exp2f(x);
}

// ---------------------------------------------------------------------------
// Block-wide sum over 256 threads (4 waves). All threads return the total.
// ---------------------------------------------------------------------------
__device__ __forceinline__ float block_sum256(float v, float* red, int t) {
#pragma unroll
  for (int o = 32; o > 0; o >>= 1) v += __shfl_down(v, o, 64);
  if ((t & 63) == 0) red[t >> 6] = v;
  __syncthreads();
  float r = red[0] + red[1] + red[2] + red[3];
  __syncthreads();
  return r;
}

// ---------------------------------------------------------------------------
// Prep kernel — 256 blocks x 256 threads. Every block redundantly computes
// the tiny rhs vector in LDS, then block hb computes w2r[hb] =
// dot(Wx2[hb,:], rhs) with a coalesced 4KB row read.
// Output (SoA, constants FOLDED so main's inner loop is minimal):
//   ws[       h] = K2LOG2E * Wx1[0][h]
//   ws[ 256 + h] = K2LOG2E * Wx1[1][h]
//   ws[ 512 + h] = K2LOG2E * Wx1[2][h]
//   ws[ 768 + h] = K2LOG2E * bx1[h]
//   ws[1024 + h] = -2 * w2r[h]
//   ws[1280]     = b2r = dot(bx2, rhs)
// ---------------------------------------------------------------------------
__global__ __launch_bounds__(256) void prep_kernel(
    const float* __restrict__ eq,
    const float* __restrict__ q0, const float* __restrict__ q1,
    const float* __restrict__ q2, const float* __restrict__ q3,
    const float* __restrict__ q4,
    const float* __restrict__ Wx1, const float* __restrict__ bx1,
    const float* __restrict__ Wx2, const float* __restrict__ bx2,
    const float* __restrict__ Wq0, const float* __restrict__ bq0,
    const float* __restrict__ Wq1, const float* __restrict__ bq1,
    const float* __restrict__ Wq2, const float* __restrict__ bq2,
    const float* __restrict__ Wq3, const float* __restrict__ bq3,
    const float* __restrict__ Wq4, const float* __restrict__ bq4,
    float* __restrict__ ws) {
  __shared__ float sS[5][64];
  __shared__ float sRhs[P5];
  __shared__ float sPart[4][10];
  __shared__ float sAB[10];
  __shared__ float red[4];

  const int t = threadIdx.x;
  const int hb = blockIdx.x;
  const float c = -eq[0] * LOG2E;  // y = exp(-x^2*eq) = exp2(x^2 * c)

  const float* qs[5]  = {q0, q1, q2, q3, q4};
  const float* Wqs[5] = {Wq0, Wq1, Wq2, Wq3, Wq4};
  const float* bqs[5] = {bq0, bq1, bq2, bq3, bq4};

  // A_i = sum_r y*qx (v[2i]), B_i = sum_r y (v[2i+1])
  float v[10];
#pragma unroll
  for (int i = 0; i < 5; ++i) {
    float a = 0.f, b = 0.f;
    if (t < NQ) {
      float x = qs[i][t];
      float y = fast_exp2(x * x * c);
      a = y * x;
      b = y;
    }
    v[2 * i] = a;
    v[2 * i + 1] = b;
  }
#pragma unroll
  for (int k = 0; k < 10; ++k) {
    float s = v[k];
#pragma unroll
    for (int o = 32; o > 0; o >>= 1) s += __shfl_down(s, o, 64);
    if ((t & 63) == 0) sPart[t >> 6][k] = s;
  }
  __syncthreads();
  if (t < 10) sAB[t] = sPart[0][t] + sPart[1][t] + sPart[2][t] + sPart[3][t];
  __syncthreads();

  // s_i[j] = Wq_i[j]*A_i + bq_i[j]*B_i   (5 x 64)
  for (int k = t; k < 5 * 64; k += 256) {
    int i = k >> 6, j = k & 63;
    sS[i][j] = Wqs[i][j] * sAB[2 * i] + bqs[i][j] * sAB[2 * i + 1];
  }
  __syncthreads();

  // rhs[idx] = sum_x s0[b,x] s1[d,x] s2[f,x] s3[m,x] s4[v,x]
  for (int idx = t; idx < P5; idx += 256) {
    int b = (idx >> 8) & 3, d = (idx >> 6) & 3, f = (idx >> 4) & 3,
        m = (idx >> 2) & 3, w = idx & 3;
    float s = 0.f;
#pragma unroll
    for (int x = 0; x < QQ; ++x)
      s += sS[0][b * QQ + x] * sS[1][d * QQ + x] * sS[2][f * QQ + x] *
           sS[3][m * QQ + x] * sS[4][w * QQ + x];
    sRhs[idx] = s;
  }
  __syncthreads();

  // w2r[hb] = dot(Wx2[hb,:], rhs)
  const float* wrow = Wx2 + hb * P5;
  float p = 0.f;
#pragma unroll
  for (int k = 0; k < 4; ++k)
    p = fmaf(wrow[t + 256 * k], sRhs[t + 256 * k], p);
  p = block_sum256(p, red, t);

  if (t == 0) {
    ws[hb]          = K2LOG2E * Wx1[hb];
    ws[HH + hb]     = K2LOG2E * Wx1[HH + hb];
    ws[2 * HH + hb] = K2LOG2E * Wx1[2 * HH + hb];
    ws[3 * HH + hb] = K2LOG2E * bx1[hb];
    ws[4 * HH + hb] = -2.0f * p;
  }

  if (hb == 0) {
    float pb = 0.f;
    for (int j = t; j < P5; j += 256) pb = fmaf(bx2[j], sRhs[j], pb);
    pb = block_sum256(pb, red, t);
    if (t == 0) ws[5 * HH] = pb;
  }
}

// ---------------------------------------------------------------------------
// Main kernel: out[i] = CONST + sum_h wr'[h] / (1 + exp2(x_i.w'_h + b'_h))
// where wr' = -2*w2r, CONST = b2r + Sum w2r = b2r - 0.5*Sum wr'.
// Identical structure to round 6 (4 waves split h, R=4 rows/lane, 391
// blocks); the ONLY change is raw v_exp_f32 via __builtin_amdgcn_exp2f in
// the inner loop, eliminating ~5 VALU insts/sigmoid of ocml denormal
// handling (theory: that wrapper made the loop VALU-issue-bound).
// ---------------------------------------------------------------------------
__global__ __launch_bounds__(256) void main_kernel(
    const float* __restrict__ input, const float* __restrict__ ws,
    float* __restrict__ out, int n) {
  __shared__ float4 qtab[HH];         // {w0,w1,w2,b} (K2LOG2E folded)
  __shared__ float4 wtab4[HH / 4];    // -2*w2r
  __shared__ float red[4];
  __shared__ float sred[4][4][64];    // [wave][r][lane] partials

  const int t = threadIdx.x;
  const int lane = t & 63;
  const int wv = t >> 6;

  // ---- stage table (thread t owns h = t; coalesced global reads) ----
  const float w0 = ws[t], w1 = ws[HH + t], w2 = ws[2 * HH + t];
  const float bb = ws[3 * HH + t], wr = ws[4 * HH + t];
  qtab[t] = make_float4(w0, w1, w2, bb);
  ((float*)wtab4)[t] = wr;

  // butterfly Sum wr within each wave; combine across waves via red[]
  float s = wr;
#pragma unroll
  for (int o = 32; o > 0; o >>= 1) s += __shfl_xor(s, o, 64);
  if (lane == 0) red[wv] = s;
  __syncthreads();  // covers qtab/wtab4/red
  const float CONST = fmaf(-0.5f, (red[0] + red[1]) + (red[2] + red[3]),
                           ws[5 * HH]);

  // ---- 4 rows per lane (same 256 rows for all 4 waves; h differs) ----
  const int row0 = blockIdx.x * 256;
  float x0[4], x1[4], x2[4], acc[4];
#pragma unroll
  for (int r = 0; r < 4; ++r) {
    const int row = row0 + r * 64 + lane;
    x0[r] = x1[r] = x2[r] = 0.f;
    if (row < n) {
      x0[r] = input[row * 3 + 0];
      x1[r] = input[row * 3 + 1];
      x2[r] = input[row * 3 + 2];
    }
    acc[r] = 0.f;
  }

  const int hbase = wv * 64;
#pragma unroll 4
  for (int j = 0; j < 16; ++j) {
    const float4 wq = wtab4[wv * 16 + j];
    const float wrv[4] = {wq.x, wq.y, wq.z, wq.w};
#pragma unroll
    for (int u = 0; u < 4; ++u) {
      const float4 q = qtab[hbase + j * 4 + u];
#pragma unroll
      for (int r = 0; r < 4; ++r) {
        float a = fmaf(q.z, x2[r], fmaf(q.y, x1[r], fmaf(q.x, x0[r], q.w)));
        float rc = __builtin_amdgcn_rcpf(fast_exp2(a) + 1.0f);  // inf -> 0
        acc[r] = fmaf(wrv[u], rc, acc[r]);
      }
    }
  }

  // ---- combine the 4 waves' h-partials ----
#pragma unroll
  for (int r = 0; r < 4; ++r) sred[wv][r][lane] = acc[r];
  __syncthreads();

  {  // thread t finalizes row group rr = t>>6, lane = t&63
    const int rr = wv;
    const int row = row0 + rr * 64 + lane;
    if (row < n) {
      float sum = (sred[0][rr][lane] + sred[1][rr][lane]) +
                  (sred[2][rr][lane] + sred[3][rr][lane]);
      out[row] = sum + CONST;
    }
  }
}

// ---------------------------------------------------------------------------
extern "C" void kernel_launch(void* const* d_in, const int* in_sizes, int n_in,
                              void* d_out, int out_size, void* d_ws,
                              size_t ws_size, hipStream_t stream) {
  const float* input = (const float*)d_in[0];
  const float* eq    = (const float*)d_in[1];
  const float* q0    = (const float*)d_in[2];
  const float* q1    = (const float*)d_in[3];
  const float* q2    = (const float*)d_in[4];
  const float* q3    = (const float*)d_in[5];
  const float* q4    = (const float*)d_in[6];
  const float* Wx1   = (const float*)d_in[7];
  const float* bx1   = (const float*)d_in[8];
  const float* Wx2   = (const float*)d_in[9];
  const float* bx2   = (const float*)d_in[10];
  const float* Wq0   = (const float*)d_in[11];
  const float* bq0   = (const float*)d_in[12];
  const float* Wq1   = (const float*)d_in[13];
  const float* bq1   = (const float*)d_in[14];
  const float* Wq2   = (const float*)d_in[15];
  const float* bq2   = (const float*)d_in[16];
  const float* Wq3   = (const float*)d_in[17];
  const float* bq3   = (const float*)d_in[18];
  const float* Wq4   = (const float*)d_in[19];
  const float* bq4   = (const float*)d_in[20];

  float* ws  = (float*)d_ws;
  float* out = (float*)d_out;
  const int n = in_sizes[0] / 3;  // N = 100000

  hipLaunchKernelGGL(prep_kernel, dim3(HH), dim3(256), 0, stream,
                     eq, q0, q1, q2, q3, q4, Wx1, bx1, Wx2, bx2,
                     Wq0, bq0, Wq1, bq1, Wq2, bq2, Wq3, bq3, Wq4, bq4, ws);

  const int blocks = (n + 255) / 256;  // 256 rows per block (R=4 per lane)
  hipLaunchKernelGGL(main_kernel, dim3(blocks), dim3(256), 0, stream,
                     input, ws, out, n);
}